// Round 8
// baseline (422.045 us; speedup 1.0000x reference)
//
#include <hip/hip_runtime.h>
#include <hip/hip_fp16.h>

// GCNWithJK on MI355X.
// Layers collapse to one GEMM each: W_eff = 0.95*W + 0.05*Wr (linearity of Agg).
// All activations fp16; GEMMs use v_mfma_f32_16x16x32_f16 (fp32 accum).
// CSR: count -> padded scan (rows padded to x16) -> XCD-partitioned fill.
// Aggregate: XCD-affine FEATURE-chunked gather — blockIdx%8 -> (chunk 0..3, half 0..1);
// each XCD gathers only a 64B chunk of each row => 3.2MB sub-table is L2-resident
// (reuse factor 16 instead of 2). recs NT-load / h NT-store keep streams out of L2.

#define FEAT 128

typedef _Float16 half8 __attribute__((ext_vector_type(8)));
typedef _Float16 half4 __attribute__((ext_vector_type(4)));
typedef float f32x4 __attribute__((ext_vector_type(4)));

__device__ __forceinline__ int lower_bound_i(const int* a, int n, int key) {
  int lo = 0, hi = n;
  while (lo < hi) { int mid = (lo + hi) >> 1; if (a[mid] < key) lo = mid + 1; else hi = mid; }
  return lo;
}

__device__ __forceinline__ float rec_w(unsigned int rc) {
  return (float)__builtin_bit_cast(_Float16, (unsigned short)(rc >> 16));
}

// ---- x fp32 -> fp16 ----
__global__ void f2h(const float* __restrict__ in, __half* __restrict__ out, int n4) {
  int i = blockIdx.x * blockDim.x + threadIdx.x;
  if (i < n4) {
    float4 v = *((const float4*)in + i);
    half4 h = { (_Float16)v.x, (_Float16)v.y, (_Float16)v.z, (_Float16)v.w };
    *((half4*)out + i) = h;
  }
}

// ---- weight prep: blend + transpose -> fp16 (Wt[c][k] = 0.95*W[k][c]+0.05*Wr[k][c]) ----
__global__ void prep_weights(const float* __restrict__ w1, const float* __restrict__ wr1,
                             const float* __restrict__ b1, const float* __restrict__ br1,
                             const float* __restrict__ w2, const float* __restrict__ b2,
                             const float* __restrict__ w3, const float* __restrict__ b3,
                             const float* __restrict__ wr, const float* __restrict__ br,
                             __half* __restrict__ Wt, float* __restrict__ beff) {
  __shared__ float tile[128][129];
  int l = blockIdx.x;
  const float* W  = (l == 0) ? w1 : ((l == 1) ? w2 : w3);
  const float* Wr = (l == 0) ? wr1 : wr;
  const float* B  = (l == 0) ? b1 : ((l == 1) ? b2 : b3);
  const float* Br = (l == 0) ? br1 : br;
  int t = threadIdx.x;
  for (int idx = t; idx < 128 * 128; idx += 256) {
    int k = idx >> 7, c = idx & 127;
    tile[k][c] = 0.95f * W[idx] + 0.05f * Wr[idx];
  }
  __syncthreads();
  __half* out = Wt + l * 128 * 128;
  for (int idx = t; idx < 128 * 128; idx += 256) {
    int c = idx >> 7, k = idx & 127;
    out[idx] = __float2half(tile[k][c]);
  }
  if (t < 128) beff[l * 128 + t] = 0.95f * B[t] + 0.05f * Br[t];
}

// ---- CSR build ----
__global__ void count_edges(const int* __restrict__ row, int E, int* __restrict__ cnt) {
  int e = blockIdx.x * blockDim.x + threadIdx.x;
  if (e < E) atomicAdd(&cnt[__builtin_nontemporal_load(&row[e])], 1);
}

__global__ void compute_dinv(const int* __restrict__ cnt, int n, float* __restrict__ dinv) {
  int i = blockIdx.x * blockDim.x + threadIdx.x;
  if (i < n) dinv[i] = rsqrtf((float)cnt[i] + 1.0f);  // +1 self-loop
}

// padded count: round each row up to a multiple of 16 (zero-recs fill the gap)
__global__ void scan1(const int* __restrict__ cnt, int n, int* __restrict__ bsum) {
  __shared__ int sdata[1024];
  int i = blockIdx.x * 1024 + threadIdx.x;
  sdata[threadIdx.x] = (i < n) ? ((cnt[i] + 15) & ~15) : 0;
  __syncthreads();
  for (int s = 512; s > 0; s >>= 1) {
    if (threadIdx.x < s) sdata[threadIdx.x] += sdata[threadIdx.x + s];
    __syncthreads();
  }
  if (threadIdx.x == 0) bsum[blockIdx.x] = sdata[0];
}

__global__ void scan2(int* __restrict__ bsum, int nb, int* __restrict__ start, int n) {
  if (threadIdx.x == 0 && blockIdx.x == 0) {
    int acc = 0;
    for (int b = 0; b < nb; b++) { int v = bsum[b]; bsum[b] = acc; acc += v; }
    start[n] = acc;
  }
}

__global__ void scan3(const int* __restrict__ cnt, int n, const int* __restrict__ bsum,
                      int* __restrict__ start, int* __restrict__ cursor) {
  __shared__ int sdata[1024];
  int tid = threadIdx.x;
  int i = blockIdx.x * 1024 + tid;
  int v = (i < n) ? ((cnt[i] + 15) & ~15) : 0;
  sdata[tid] = v;
  __syncthreads();
  for (int off = 1; off < 1024; off <<= 1) {
    int add = (tid >= off) ? sdata[tid - off] : 0;
    __syncthreads();
    sdata[tid] += add;
    __syncthreads();
  }
  if (i < n) {
    int sv = bsum[blockIdx.x] + sdata[tid] - v;  // exclusive (padded)
    start[i] = sv;
    cursor[i] = sv;
  }
}

// ---- XCD-partitioned fill: block b -> group g=b&7 (row range), slice s=b>>3 ----
__global__ __launch_bounds__(256) void fill_part(const int* __restrict__ edge, int E,
                                                 const float* __restrict__ dinv,
                                                 int* __restrict__ cursor,
                                                 unsigned int* __restrict__ recs,
                                                 int n, int nslice) {
  int b = blockIdx.x;
  int g = b & 7;
  int s = b >> 3;
  int rpg = n >> 3;                      // 6250
  int rlo = g * rpg;
  int rhi = (g == 7) ? n : rlo + rpg;
  long long e0 = (long long)E * s / nslice;
  long long e1 = (long long)E * (s + 1) / nslice;
  for (int e = (int)e0 + threadIdx.x; e < (int)e1; e += 256) {
    int r = __builtin_nontemporal_load(&edge[e]);
    if (r >= rlo && r < rhi) {
      int c = __builtin_nontemporal_load(&edge[E + e]);
      int pos = atomicAdd(&cursor[r], 1);
      unsigned short wb = __builtin_bit_cast(unsigned short, (_Float16)(dinv[r] * dinv[c]));
      recs[pos] = (unsigned int)c | ((unsigned int)wb << 16);
    }
  }
}

// ---- MFMA GEMM: xwh[r][c] = fp16( sum_k Xh[r][k] * Wt[c][k] ) ----
__global__ __launch_bounds__(256) void gemm_mfma(const __half* __restrict__ Xh,
                                                 const __half* __restrict__ Wt,
                                                 __half* __restrict__ xwh, int ntile) {
  __shared__ __half Wlds[128 * 128];
  int t = threadIdx.x;
  #pragma unroll
  for (int it = 0; it < 8; it++) {
    int idx = t + it * 256;          // 2048 chunks of 16B
    int c = idx >> 4, ch = idx & 15;
    float4 v = *((const float4*)Wt + idx);
    int byte = ((c << 8) + (ch << 4)) ^ ((c & 7) << 4);
    *(float4*)((char*)Wlds + byte) = v;
  }
  __syncthreads();

  int wid = t >> 6, lane = t & 63;
  int tile = blockIdx.x * 4 + wid;
  if (tile >= ntile) return;
  int r = lane & 15, kg = lane >> 4;
  size_t rowbase = (size_t)tile * 16;

  const half8* aptr = (const half8*)(Xh + (rowbase + r) * FEAT + kg * 8);
  half8 a[4];
  #pragma unroll
  for (int ks = 0; ks < 4; ks++) a[ks] = aptr[ks * 4];   // k0 = ks*32 + kg*8

  f32x4 acc[8];
  #pragma unroll
  for (int nt = 0; nt < 8; nt++) acc[nt] = (f32x4){0.f, 0.f, 0.f, 0.f};

  #pragma unroll
  for (int nt = 0; nt < 8; nt++) {
    #pragma unroll
    for (int ks = 0; ks < 4; ks++) {
      int byte = ((((nt << 4) + r) << 8) + (ks << 6) + (kg << 4)) ^ ((r & 7) << 4);
      half8 b = *(const half8*)((const char*)Wlds + byte);
      acc[nt] = __builtin_amdgcn_mfma_f32_16x16x32_f16(a[ks], b, acc[nt], 0, 0, 0);
    }
  }

  int orow = kg * 4;
  #pragma unroll
  for (int nt = 0; nt < 8; nt++)
    #pragma unroll
    for (int j = 0; j < 4; j++)
      xwh[(rowbase + orow + j) * FEAT + (nt << 4) + r] = __float2half(acc[nt][j]);
}

// ---- XCD-affine feature-chunked aggregation ----
// blockIdx%8 -> m: chunk = m>>1 (32 feats = 64B of each row), half = m&1 (node range).
// Each XCD gathers ONLY its 64B chunk => 3.2MB sub-table L2-resident (16x reuse).
// Wave = 1 node; lane = (feat 0..31, edge-parity); 16 padded edges/iter in flight.
__global__ __launch_bounds__(256) void aggregate_chunk(
    const __half* __restrict__ xwh, const unsigned int* __restrict__ recs,
    const int* __restrict__ start, const float* __restrict__ dinv,
    const float* __restrict__ beff, __half* __restrict__ h, int n) {
  int b = blockIdx.x;
  int m = b & 7;
  int chunk = m >> 1;
  int half = m & 1;
  int n_half = (n + 1) >> 1;
  int wid = threadIdx.x >> 6, lane = threadIdx.x & 63;
  int node = half * n_half + (b >> 3) * 4 + wid;
  int hi = half ? n : n_half;
  if (node >= hi) return;

  int f = lane & 31;          // feature within chunk
  int ep = lane >> 5;         // edge parity (0/1)
  int col = chunk * 32 + f;   // absolute feature 0..127

  float acc = 0.f;
  int s = start[node], e = start[node + 1];   // e - s is a multiple of 16
  for (int idx = s; idx + 16 <= e; idx += 16) {
    unsigned int rc[8];
    float vv[8];
    #pragma unroll
    for (int q = 0; q < 8; q++)
      rc[q] = __builtin_nontemporal_load(&recs[idx + 2 * q + ep]);
    #pragma unroll
    for (int q = 0; q < 8; q++)
      vv[q] = (float)xwh[(size_t)(rc[q] & 0xffffu) * FEAT + col];
    #pragma unroll
    for (int q = 0; q < 8; q++)
      acc += rec_w(rc[q]) * vv[q];
  }
  // fold the two edge-parity partial sums: lanes l and l^32 hold same feature
  acc += __shfl_xor(acc, 32, 64);
  if (ep == 0) {
    float di = dinv[node];
    float self = (float)xwh[(size_t)node * FEAT + col] * di * di;
    float a = fmaxf(acc + self + beff[col], 0.f);
    unsigned short hv = __builtin_bit_cast(unsigned short, (_Float16)a);
    __builtin_nontemporal_store(hv, (unsigned short*)(h + (size_t)node * FEAT + col));
  }
}

// ---- fused mean-pool + lin1 + relu + lin2 + log_softmax (256 threads) ----
__global__ __launch_bounds__(256) void pool_mlp(
    const __half* __restrict__ h1, const __half* __restrict__ h2,
    const __half* __restrict__ h3, const int* __restrict__ batch, int n,
    const float* __restrict__ lin1w, const float* __restrict__ lin1b,
    const float* __restrict__ lin2w, const float* __restrict__ lin2b,
    float* __restrict__ out) {
  __shared__ float part[8][384];
  __shared__ float mean[384];
  __shared__ float tvec[128];
  __shared__ float logits[10];
  __shared__ float red[2];
  int g = blockIdx.x;
  int t = threadIdx.x;   // 256 threads
  int lo = lower_bound_i(batch, n, g);
  int hi = lower_bound_i(batch, n, g + 1);
  int rg = t >> 5, f4 = t & 31;
  float s1[4] = {0,0,0,0}, s2[4] = {0,0,0,0}, s3[4] = {0,0,0,0};
  for (int i = lo + rg; i < hi; i += 8) {
    half4 v1 = *((const half4*)(h1 + (size_t)i * FEAT) + f4);
    half4 v2 = *((const half4*)(h2 + (size_t)i * FEAT) + f4);
    half4 v3 = *((const half4*)(h3 + (size_t)i * FEAT) + f4);
    #pragma unroll
    for (int q = 0; q < 4; q++) {
      s1[q] += (float)v1[q]; s2[q] += (float)v2[q]; s3[q] += (float)v3[q];
    }
  }
  #pragma unroll
  for (int q = 0; q < 4; q++) {
    part[rg][f4 * 4 + q]       = s1[q];
    part[rg][128 + f4 * 4 + q] = s2[q];
    part[rg][256 + f4 * 4 + q] = s3[q];
  }
  __syncthreads();
  float invc = 1.0f / fmaxf((float)(hi - lo), 1.0f);
  for (int j = t; j < 384; j += 256) {
    float acc = 0.f;
    #pragma unroll
    for (int r = 0; r < 8; r++) acc += part[r][j];
    mean[j] = acc * invc;
  }
  __syncthreads();
  if (t < 128) {
    float acc = lin1b[t];
    for (int k = 0; k < 384; k++) acc += mean[k] * lin1w[k * 128 + t];
    tvec[t] = fmaxf(acc, 0.f);
  }
  __syncthreads();
  if (t < 10) {
    float a = lin2b[t];
    for (int k = 0; k < 128; k++) a += tvec[k] * lin2w[k * 10 + t];
    logits[t] = a;
  }
  __syncthreads();
  if (t == 0) {
    float m = -1e30f;
    for (int j = 0; j < 10; j++) m = fmaxf(m, logits[j]);
    float se = 0.f;
    for (int j = 0; j < 10; j++) se += expf(logits[j] - m);
    red[0] = m; red[1] = logf(se);
  }
  __syncthreads();
  if (t < 10) out[g * 10 + t] = logits[t] - red[0] - red[1];
}

extern "C" void kernel_launch(void* const* d_in, const int* in_sizes, int n_in,
                              void* d_out, int out_size, void* d_ws, size_t ws_size,
                              hipStream_t stream) {
  const float* x     = (const float*)d_in[0];
  const int*   edge  = (const int*)d_in[1];
  const int*   batch = (const int*)d_in[2];
  const float* w1    = (const float*)d_in[3];
  const float* b1    = (const float*)d_in[4];
  const float* wr1   = (const float*)d_in[5];
  const float* br1   = (const float*)d_in[6];
  const float* w2    = (const float*)d_in[7];
  const float* b2    = (const float*)d_in[8];
  const float* w3    = (const float*)d_in[9];
  const float* b3    = (const float*)d_in[10];
  const float* wr    = (const float*)d_in[11];
  const float* br    = (const float*)d_in[12];
  const float* lin1w = (const float*)d_in[13];
  const float* lin1b = (const float*)d_in[14];
  const float* lin2w = (const float*)d_in[15];
  const float* lin2b = (const float*)d_in[16];

  int n  = in_sizes[0] / FEAT;   // 50000
  int E  = in_sizes[1] / 2;      // 800000
  int ng = out_size / 10;        // 512

  char* p = (char*)d_ws;
  auto carve = [&](size_t bytes) -> void* {
    void* r = (void*)p;
    p += (bytes + 255) & ~(size_t)255;
    return r;
  };
  size_t recs_cap = (size_t)E + 16 * (size_t)n;   // padded upper bound
  __half*       Wt     = (__half*)carve(3 * 128 * 128 * sizeof(__half));
  float*        beff   = (float*)carve(3 * 128 * sizeof(float));
  int*          cnt    = (int*)carve((size_t)n * sizeof(int));
  int*          cursor = (int*)carve((size_t)n * sizeof(int));
  int*          start  = (int*)carve((size_t)(n + 1) * sizeof(int));
  int*          bsum   = (int*)carve(64 * sizeof(int));
  unsigned int* recs   = (unsigned int*)carve(recs_cap * sizeof(unsigned int));
  float*        dinv   = (float*)carve((size_t)n * sizeof(float));
  __half*       xh     = (__half*)carve((size_t)n * FEAT * sizeof(__half));
  __half*       xwh    = (__half*)carve((size_t)n * FEAT * sizeof(__half));
  __half*       h1     = (__half*)carve((size_t)n * FEAT * sizeof(__half));
  __half*       h2     = (__half*)carve((size_t)n * FEAT * sizeof(__half));
  __half*       h3     = (__half*)carve((size_t)n * FEAT * sizeof(__half));

  hipMemsetAsync(cnt, 0, (size_t)n * sizeof(int), stream);
  hipMemsetAsync(recs, 0, recs_cap * sizeof(unsigned int), stream);

  prep_weights<<<3, 256, 0, stream>>>(w1, wr1, b1, br1, w2, b2, w3, b3, wr, br, Wt, beff);

  int n4 = n * FEAT / 4;
  f2h<<<(n4 + 255) / 256, 256, 0, stream>>>(x, xh, n4);

  int eb = (E + 255) / 256;
  count_edges<<<eb, 256, 0, stream>>>(edge, E, cnt);
  compute_dinv<<<(n + 255) / 256, 256, 0, stream>>>(cnt, n, dinv);
  int nb = (n + 1023) / 1024;
  scan1<<<nb, 1024, 0, stream>>>(cnt, n, bsum);
  scan2<<<1, 64, 0, stream>>>(bsum, nb, start, n);
  scan3<<<nb, 1024, 0, stream>>>(cnt, n, bsum, start, cursor);

  int nslice = 256;                     // 8 groups x 256 slices = 2048 blocks
  fill_part<<<8 * nslice, 256, 0, stream>>>(edge, E, dinv, cursor, recs, n, nslice);

  int ntile = (n + 15) / 16;            // 3125
  int gb = (ntile + 3) / 4;             // 4 waves/block
  int n_half = (n + 1) >> 1;
  int ab = 8 * ((n_half + 3) / 4);      // 8 XCD slots x node-batches of 4

  gemm_mfma<<<gb, 256, 0, stream>>>(xh, Wt, xwh, ntile);
  aggregate_chunk<<<ab, 256, 0, stream>>>(xwh, recs, start, dinv, beff, h1, n);

  gemm_mfma<<<gb, 256, 0, stream>>>(h1, Wt + 128 * 128, xwh, ntile);
  aggregate_chunk<<<ab, 256, 0, stream>>>(xwh, recs, start, dinv, beff + 128, h2, n);

  gemm_mfma<<<gb, 256, 0, stream>>>(h2, Wt + 2 * 128 * 128, xwh, ntile);
  aggregate_chunk<<<ab, 256, 0, stream>>>(xwh, recs, start, dinv, beff + 256, h3, n);

  pool_mlp<<<ng, 256, 0, stream>>>(h1, h2, h3, batch, n, lin1w, lin1b, lin2w, lin2b,
                                   (float*)d_out);
}

// Round 9
// 288.272 us; speedup vs baseline: 1.4641x; 1.4641x over previous
//
#include <hip/hip_runtime.h>
#include <hip/hip_fp16.h>

// GCNWithJK on MI355X.
// Layers collapse to one GEMM each: W_eff = 0.95*W + 0.05*Wr (linearity of Agg).
// All activations fp16; GEMMs use v_mfma_f32_16x16x32_f16 (fp32 accum).
// CSR build (two-pass, XCD-affine):
//   pass0 group-count -> scan8 -> pass1 partition into 8 row-range buckets
//   (block-compacted coalesced writes) -> count_rows (XCD-local atomics) ->
//   dinv -> padded scan (x8) -> pass2 fill (bucket g on XCD g: stream+recs L2-fit
//   => each dirty line written back once).
// Aggregate: full-row pull (one wave/node, 8 gathers in flight, pad slots read
// row 0 with w=0 => exact no-op).

#define FEAT 128

typedef _Float16 half8 __attribute__((ext_vector_type(8)));
typedef _Float16 half4 __attribute__((ext_vector_type(4)));
typedef float f32x4 __attribute__((ext_vector_type(4)));

__device__ __forceinline__ int lower_bound_i(const int* a, int n, int key) {
  int lo = 0, hi = n;
  while (lo < hi) { int mid = (lo + hi) >> 1; if (a[mid] < key) lo = mid + 1; else hi = mid; }
  return lo;
}

__device__ __forceinline__ float rec_w(unsigned int rc) {
  return (float)__builtin_bit_cast(_Float16, (unsigned short)(rc >> 16));
}

// ---- x fp32 -> fp16 ----
__global__ void f2h(const float* __restrict__ in, __half* __restrict__ out, int n4) {
  int i = blockIdx.x * blockDim.x + threadIdx.x;
  if (i < n4) {
    float4 v = *((const float4*)in + i);
    half4 h = { (_Float16)v.x, (_Float16)v.y, (_Float16)v.z, (_Float16)v.w };
    *((half4*)out + i) = h;
  }
}

// ---- weight prep: blend + transpose -> fp16 ----
__global__ void prep_weights(const float* __restrict__ w1, const float* __restrict__ wr1,
                             const float* __restrict__ b1, const float* __restrict__ br1,
                             const float* __restrict__ w2, const float* __restrict__ b2,
                             const float* __restrict__ w3, const float* __restrict__ b3,
                             const float* __restrict__ wr, const float* __restrict__ br,
                             __half* __restrict__ Wt, float* __restrict__ beff) {
  __shared__ float tile[128][129];
  int l = blockIdx.x;
  const float* W  = (l == 0) ? w1 : ((l == 1) ? w2 : w3);
  const float* Wr = (l == 0) ? wr1 : wr;
  const float* B  = (l == 0) ? b1 : ((l == 1) ? b2 : b3);
  const float* Br = (l == 0) ? br1 : br;
  int t = threadIdx.x;
  for (int idx = t; idx < 128 * 128; idx += 256) {
    int k = idx >> 7, c = idx & 127;
    tile[k][c] = 0.95f * W[idx] + 0.05f * Wr[idx];
  }
  __syncthreads();
  __half* out = Wt + l * 128 * 128;
  for (int idx = t; idx < 128 * 128; idx += 256) {
    int c = idx >> 7, k = idx & 127;
    out[idx] = __float2half(tile[k][c]);
  }
  if (t < 128) beff[l * 128 + t] = 0.95f * B[t] + 0.05f * Br[t];
}

// ---- pass 0: per-group edge counts ----
__global__ __launch_bounds__(256) void group_count(const int* __restrict__ edge, int E,
                                                   int* __restrict__ gcnt, int rpg) {
  __shared__ int cnt8[8];
  int t = threadIdx.x;
  if (t < 8) cnt8[t] = 0;
  __syncthreads();
  long long e0 = (long long)E * blockIdx.x / gridDim.x;
  long long e1 = (long long)E * (blockIdx.x + 1) / gridDim.x;
  for (int e = (int)e0 + t; e < (int)e1; e += 256) {
    int r = __builtin_nontemporal_load(&edge[e]);
    atomicAdd(&cnt8[min(r / rpg, 7)], 1);
  }
  __syncthreads();
  if (t < 8) atomicAdd(&gcnt[t], cnt8[t]);
}

__global__ void scan8(const int* __restrict__ gcnt, int* __restrict__ goff,
                      int* __restrict__ gcur) {
  if (threadIdx.x == 0) {
    int acc = 0;
    for (int g = 0; g < 8; g++) { goff[g] = acc; gcur[g] = acc; acc += gcnt[g]; }
  }
}

// ---- pass 1: partition edges into 8 contiguous row-range buckets ----
__global__ __launch_bounds__(256) void partition_edges(const int* __restrict__ edge, int E,
                                                       int* __restrict__ gcur,
                                                       int* __restrict__ br,
                                                       int* __restrict__ bc, int rpg) {
  __shared__ int cnt8[8], base8[8], cur8[8];
  int t = threadIdx.x;
  if (t < 8) { cnt8[t] = 0; cur8[t] = 0; }
  __syncthreads();
  long long e0 = (long long)E * blockIdx.x / gridDim.x;
  long long e1 = (long long)E * (blockIdx.x + 1) / gridDim.x;
  for (int e = (int)e0 + t; e < (int)e1; e += 256) {
    int r = __builtin_nontemporal_load(&edge[e]);
    atomicAdd(&cnt8[min(r / rpg, 7)], 1);
  }
  __syncthreads();
  if (t < 8) base8[t] = atomicAdd(&gcur[t], cnt8[t]);
  __syncthreads();
  for (int e = (int)e0 + t; e < (int)e1; e += 256) {
    int r = __builtin_nontemporal_load(&edge[e]);
    int c = __builtin_nontemporal_load(&edge[E + e]);
    int g = min(r / rpg, 7);
    int p = base8[g] + atomicAdd(&cur8[g], 1);
    br[p] = r;
    bc[p] = c;
  }
}

// ---- per-row counts from bucketed rows (XCD-local atomic region) ----
__global__ __launch_bounds__(256) void count_rows(const int* __restrict__ br,
                                                  const int* __restrict__ goff,
                                                  const int* __restrict__ gcnt,
                                                  int* __restrict__ cnt, int nslice) {
  int g = blockIdx.x & 7, s = blockIdx.x >> 3;
  int lo = goff[g], c = gcnt[g];
  long long i0 = lo + (long long)c * s / nslice;
  long long i1 = lo + (long long)c * (s + 1) / nslice;
  for (int i = (int)i0 + threadIdx.x; i < (int)i1; i += 256)
    atomicAdd(&cnt[__builtin_nontemporal_load(&br[i])], 1);
}

__global__ void compute_dinv(const int* __restrict__ cnt, int n, float* __restrict__ dinv) {
  int i = blockIdx.x * blockDim.x + threadIdx.x;
  if (i < n) dinv[i] = rsqrtf((float)cnt[i] + 1.0f);  // +1 self-loop
}

// padded count: round each row up to a multiple of 8 (zero-recs fill the gap)
__global__ void scan1(const int* __restrict__ cnt, int n, int* __restrict__ bsum) {
  __shared__ int sdata[1024];
  int i = blockIdx.x * 1024 + threadIdx.x;
  sdata[threadIdx.x] = (i < n) ? ((cnt[i] + 7) & ~7) : 0;
  __syncthreads();
  for (int s = 512; s > 0; s >>= 1) {
    if (threadIdx.x < s) sdata[threadIdx.x] += sdata[threadIdx.x + s];
    __syncthreads();
  }
  if (threadIdx.x == 0) bsum[blockIdx.x] = sdata[0];
}

// single-wave exclusive scan over block sums (nb <= 64)
__global__ void scan2(int* __restrict__ bsum, int nb, int* __restrict__ start, int n) {
  int t = threadIdx.x;   // 64 threads
  int v = (t < nb) ? bsum[t] : 0;
  int s = v;
  for (int d = 1; d < 64; d <<= 1) {
    int o = __shfl_up(s, d, 64);
    if (t >= d) s += o;
  }
  if (t < nb) bsum[t] = s - v;   // exclusive
  if (t == 63) start[n] = s;     // grand total
}

__global__ void scan3(const int* __restrict__ cnt, int n, const int* __restrict__ bsum,
                      int* __restrict__ start, int* __restrict__ cursor) {
  __shared__ int sdata[1024];
  int tid = threadIdx.x;
  int i = blockIdx.x * 1024 + tid;
  int v = (i < n) ? ((cnt[i] + 7) & ~7) : 0;
  sdata[tid] = v;
  __syncthreads();
  for (int off = 1; off < 1024; off <<= 1) {
    int add = (tid >= off) ? sdata[tid - off] : 0;
    __syncthreads();
    sdata[tid] += add;
    __syncthreads();
  }
  if (i < n) {
    int sv = bsum[blockIdx.x] + sdata[tid] - v;  // exclusive (padded)
    start[i] = sv;
    cursor[i] = sv;
  }
}

// ---- pass 2: fill recs from bucket g on XCD g (blockIdx%8 == g) ----
__global__ __launch_bounds__(256) void fill_bucket(const int* __restrict__ br,
                                                   const int* __restrict__ bc,
                                                   const int* __restrict__ goff,
                                                   const int* __restrict__ gcnt,
                                                   const float* __restrict__ dinv,
                                                   int* __restrict__ cursor,
                                                   unsigned int* __restrict__ recs,
                                                   int nslice) {
  int g = blockIdx.x & 7, s = blockIdx.x >> 3;
  int lo = goff[g], c = gcnt[g];
  long long i0 = lo + (long long)c * s / nslice;
  long long i1 = lo + (long long)c * (s + 1) / nslice;
  for (int i = (int)i0 + threadIdx.x; i < (int)i1; i += 256) {
    int r = __builtin_nontemporal_load(&br[i]);
    int col = __builtin_nontemporal_load(&bc[i]);
    int pos = atomicAdd(&cursor[r], 1);
    unsigned short wb = __builtin_bit_cast(unsigned short, (_Float16)(dinv[r] * dinv[col]));
    recs[pos] = (unsigned int)col | ((unsigned int)wb << 16);
  }
}

// ---- MFMA GEMM: xwh[r][c] = fp16( sum_k Xh[r][k] * Wt[c][k] ) ----
__global__ __launch_bounds__(256) void gemm_mfma(const __half* __restrict__ Xh,
                                                 const __half* __restrict__ Wt,
                                                 __half* __restrict__ xwh, int ntile) {
  __shared__ __half Wlds[128 * 128];
  int t = threadIdx.x;
  #pragma unroll
  for (int it = 0; it < 8; it++) {
    int idx = t + it * 256;          // 2048 chunks of 16B
    int c = idx >> 4, ch = idx & 15;
    float4 v = *((const float4*)Wt + idx);
    int byte = ((c << 8) + (ch << 4)) ^ ((c & 7) << 4);
    *(float4*)((char*)Wlds + byte) = v;
  }
  __syncthreads();

  int wid = t >> 6, lane = t & 63;
  int tile = blockIdx.x * 4 + wid;
  if (tile >= ntile) return;
  int r = lane & 15, kg = lane >> 4;
  size_t rowbase = (size_t)tile * 16;

  const half8* aptr = (const half8*)(Xh + (rowbase + r) * FEAT + kg * 8);
  half8 a[4];
  #pragma unroll
  for (int ks = 0; ks < 4; ks++) a[ks] = aptr[ks * 4];   // k0 = ks*32 + kg*8

  f32x4 acc[8];
  #pragma unroll
  for (int nt = 0; nt < 8; nt++) acc[nt] = (f32x4){0.f, 0.f, 0.f, 0.f};

  #pragma unroll
  for (int nt = 0; nt < 8; nt++) {
    #pragma unroll
    for (int ks = 0; ks < 4; ks++) {
      int byte = ((((nt << 4) + r) << 8) + (ks << 6) + (kg << 4)) ^ ((r & 7) << 4);
      half8 b = *(const half8*)((const char*)Wlds + byte);
      acc[nt] = __builtin_amdgcn_mfma_f32_16x16x32_f16(a[ks], b, acc[nt], 0, 0, 0);
    }
  }

  int orow = kg * 4;
  #pragma unroll
  for (int nt = 0; nt < 8; nt++)
    #pragma unroll
    for (int j = 0; j < 4; j++)
      xwh[(rowbase + orow + j) * FEAT + (nt << 4) + r] = __float2half(acc[nt][j]);
}

// ---- pull aggregation: one wave/node; rows padded to x8 -> 8 gathers in flight ----
__global__ __launch_bounds__(256) void aggregate(
    const __half* __restrict__ xwh, const unsigned int* __restrict__ recs,
    const int* __restrict__ start, const float* __restrict__ dinv,
    const float* __restrict__ beff, __half* __restrict__ h, int n) {
  int wave = (blockIdx.x * blockDim.x + threadIdx.x) >> 6;
  int lane = threadIdx.x & 63;
  if (wave >= n) return;
  float di = dinv[wave];
  float2 sv = __half22float2(*(const __half2*)(xwh + (size_t)wave * FEAT + lane * 2));
  float wii = di * di;
  float a0 = sv.x * wii;
  float a1 = sv.y * wii;
  int s = start[wave], e = start[wave + 1];   // e - s is a multiple of 8
  for (int idx = s; idx < e; idx += 8) {
    uint4 r0 = *(const uint4*)(recs + idx);
    uint4 r1 = *(const uint4*)(recs + idx + 4);
    unsigned int rc[8] = {r0.x, r0.y, r0.z, r0.w, r1.x, r1.y, r1.z, r1.w};
    float2 u[8];
    #pragma unroll
    for (int q = 0; q < 8; q++)
      u[q] = __half22float2(
          *(const __half2*)(xwh + (size_t)(rc[q] & 0xffffu) * FEAT + lane * 2));
    #pragma unroll
    for (int q = 0; q < 8; q++) {
      float w = rec_w(rc[q]);
      a0 += u[q].x * w; a1 += u[q].y * w;
    }
  }
  float2 b = *(const float2*)(beff + lane * 2);
  a0 = fmaxf(a0 + b.x, 0.f);
  a1 = fmaxf(a1 + b.y, 0.f);
  *(__half2*)(h + (size_t)wave * FEAT + lane * 2) = __float22half2_rn(make_float2(a0, a1));
}

// ---- fused mean-pool + lin1 + relu + lin2 + log_softmax (256 threads) ----
__global__ __launch_bounds__(256) void pool_mlp(
    const __half* __restrict__ h1, const __half* __restrict__ h2,
    const __half* __restrict__ h3, const int* __restrict__ batch, int n,
    const float* __restrict__ lin1w, const float* __restrict__ lin1b,
    const float* __restrict__ lin2w, const float* __restrict__ lin2b,
    float* __restrict__ out) {
  __shared__ float part[8][384];
  __shared__ float mean[384];
  __shared__ float tvec[128];
  __shared__ float logits[10];
  __shared__ float red[2];
  int g = blockIdx.x;
  int t = threadIdx.x;   // 256 threads
  int lo = lower_bound_i(batch, n, g);
  int hi = lower_bound_i(batch, n, g + 1);
  int rg = t >> 5, f4 = t & 31;
  float s1[4] = {0,0,0,0}, s2[4] = {0,0,0,0}, s3[4] = {0,0,0,0};
  for (int i = lo + rg; i < hi; i += 8) {
    half4 v1 = *((const half4*)(h1 + (size_t)i * FEAT) + f4);
    half4 v2 = *((const half4*)(h2 + (size_t)i * FEAT) + f4);
    half4 v3 = *((const half4*)(h3 + (size_t)i * FEAT) + f4);
    #pragma unroll
    for (int q = 0; q < 4; q++) {
      s1[q] += (float)v1[q]; s2[q] += (float)v2[q]; s3[q] += (float)v3[q];
    }
  }
  #pragma unroll
  for (int q = 0; q < 4; q++) {
    part[rg][f4 * 4 + q]       = s1[q];
    part[rg][128 + f4 * 4 + q] = s2[q];
    part[rg][256 + f4 * 4 + q] = s3[q];
  }
  __syncthreads();
  float invc = 1.0f / fmaxf((float)(hi - lo), 1.0f);
  for (int j = t; j < 384; j += 256) {
    float acc = 0.f;
    #pragma unroll
    for (int r = 0; r < 8; r++) acc += part[r][j];
    mean[j] = acc * invc;
  }
  __syncthreads();
  if (t < 128) {
    float acc = lin1b[t];
    for (int k = 0; k < 384; k++) acc += mean[k] * lin1w[k * 128 + t];
    tvec[t] = fmaxf(acc, 0.f);
  }
  __syncthreads();
  if (t < 10) {
    float a = lin2b[t];
    for (int k = 0; k < 128; k++) a += tvec[k] * lin2w[k * 10 + t];
    logits[t] = a;
  }
  __syncthreads();
  if (t == 0) {
    float m = -1e30f;
    for (int j = 0; j < 10; j++) m = fmaxf(m, logits[j]);
    float se = 0.f;
    for (int j = 0; j < 10; j++) se += expf(logits[j] - m);
    red[0] = m; red[1] = logf(se);
  }
  __syncthreads();
  if (t < 10) out[g * 10 + t] = logits[t] - red[0] - red[1];
}

extern "C" void kernel_launch(void* const* d_in, const int* in_sizes, int n_in,
                              void* d_out, int out_size, void* d_ws, size_t ws_size,
                              hipStream_t stream) {
  const float* x     = (const float*)d_in[0];
  const int*   edge  = (const int*)d_in[1];
  const int*   batch = (const int*)d_in[2];
  const float* w1    = (const float*)d_in[3];
  const float* b1    = (const float*)d_in[4];
  const float* wr1   = (const float*)d_in[5];
  const float* br1   = (const float*)d_in[6];
  const float* w2    = (const float*)d_in[7];
  const float* b2    = (const float*)d_in[8];
  const float* w3    = (const float*)d_in[9];
  const float* b3    = (const float*)d_in[10];
  const float* wr    = (const float*)d_in[11];
  const float* br    = (const float*)d_in[12];
  const float* lin1w = (const float*)d_in[13];
  const float* lin1b = (const float*)d_in[14];
  const float* lin2w = (const float*)d_in[15];
  const float* lin2b = (const float*)d_in[16];

  int n  = in_sizes[0] / FEAT;   // 50000
  int E  = in_sizes[1] / 2;      // 800000
  int ng = out_size / 10;        // 512
  int rpg = n >> 3;              // rows per group

  char* p = (char*)d_ws;
  auto carve = [&](size_t bytes) -> void* {
    void* r = (void*)p;
    p += (bytes + 255) & ~(size_t)255;
    return r;
  };
  size_t recs_cap = (size_t)E + 8 * (size_t)n;   // padded upper bound
  __half*       Wt     = (__half*)carve(3 * 128 * 128 * sizeof(__half));
  float*        beff   = (float*)carve(3 * 128 * sizeof(float));
  int*          cnt    = (int*)carve((size_t)n * sizeof(int));
  int*          cursor = (int*)carve((size_t)n * sizeof(int));
  int*          start  = (int*)carve((size_t)(n + 1) * sizeof(int));
  int*          bsum   = (int*)carve(64 * sizeof(int));
  int*          gcnt   = (int*)carve(8 * sizeof(int));
  int*          goff   = (int*)carve(8 * sizeof(int));
  int*          gcur   = (int*)carve(8 * sizeof(int));
  int*          brow   = (int*)carve((size_t)E * sizeof(int));
  int*          bcol   = (int*)carve((size_t)E * sizeof(int));
  unsigned int* recs   = (unsigned int*)carve(recs_cap * sizeof(unsigned int));
  float*        dinv   = (float*)carve((size_t)n * sizeof(float));
  __half*       xh     = (__half*)carve((size_t)n * FEAT * sizeof(__half));
  __half*       xwh    = (__half*)carve((size_t)n * FEAT * sizeof(__half));
  __half*       h1     = (__half*)carve((size_t)n * FEAT * sizeof(__half));
  __half*       h2     = (__half*)carve((size_t)n * FEAT * sizeof(__half));
  __half*       h3     = (__half*)carve((size_t)n * FEAT * sizeof(__half));

  hipMemsetAsync(cnt, 0, (size_t)n * sizeof(int), stream);
  hipMemsetAsync(gcnt, 0, 8 * sizeof(int), stream);
  hipMemsetAsync(recs, 0, recs_cap * sizeof(unsigned int), stream);

  prep_weights<<<3, 256, 0, stream>>>(w1, wr1, b1, br1, w2, b2, w3, b3, wr, br, Wt, beff);

  int n4 = n * FEAT / 4;
  f2h<<<(n4 + 255) / 256, 256, 0, stream>>>(x, xh, n4);

  // CSR build
  group_count<<<1024, 256, 0, stream>>>(edge, E, gcnt, rpg);
  scan8<<<1, 64, 0, stream>>>(gcnt, goff, gcur);
  partition_edges<<<1024, 256, 0, stream>>>(edge, E, gcur, brow, bcol, rpg);
  count_rows<<<1024, 256, 0, stream>>>(brow, goff, gcnt, cnt, 1024 / 8);
  compute_dinv<<<(n + 255) / 256, 256, 0, stream>>>(cnt, n, dinv);
  int nb = (n + 1023) / 1024;
  scan1<<<nb, 1024, 0, stream>>>(cnt, n, bsum);
  scan2<<<1, 64, 0, stream>>>(bsum, nb, start, n);
  scan3<<<nb, 1024, 0, stream>>>(cnt, n, bsum, start, cursor);
  fill_bucket<<<2048, 256, 0, stream>>>(brow, bcol, goff, gcnt, dinv, cursor, recs,
                                        2048 / 8);

  int ntile = (n + 15) / 16;            // 3125
  int gb = (ntile + 3) / 4;             // 4 waves/block
  int ab = (n * 64 + 255) / 256;

  gemm_mfma<<<gb, 256, 0, stream>>>(xh, Wt, xwh, ntile);
  aggregate<<<ab, 256, 0, stream>>>(xwh, recs, start, dinv, beff, h1, n);

  gemm_mfma<<<gb, 256, 0, stream>>>(h1, Wt + 128 * 128, xwh, ntile);
  aggregate<<<ab, 256, 0, stream>>>(xwh, recs, start, dinv, beff + 128, h2, n);

  gemm_mfma<<<gb, 256, 0, stream>>>(h2, Wt + 2 * 128 * 128, xwh, ntile);
  aggregate<<<ab, 256, 0, stream>>>(xwh, recs, start, dinv, beff + 256, h3, n);

  pool_mlp<<<ng, 256, 0, stream>>>(h1, h2, h3, batch, n, lin1w, lin1b, lin2w, lin2b,
                                   (float*)d_out);
}

// Round 11
// 285.647 us; speedup vs baseline: 1.4775x; 1.0092x over previous
//
#include <hip/hip_runtime.h>
#include <hip/hip_fp16.h>

// GCNWithJK on MI355X.
// Layers collapse to one GEMM each: W_eff = 0.95*W + 0.05*Wr (linearity of Agg).
// All activations fp16; GEMMs use v_mfma_f32_16x16x32_f16 (fp32 accum); layer-1
// GEMM reads fp32 x directly (in-register convert).
// CSR build (two-pass, XCD-affine): group_count -> scan8 -> partition into 8
// row-range buckets -> count_rows (XCD-local atomics) -> dinv -> padded scan (x16)
// -> fill_bucket (bucket g on XCD g: stream+recs region L2-fit).
// Aggregate: one wave/node, rows padded to x16 -> 16 gathers ALWAYS in flight
// (pad slots read row 0 with w=0: exact no-op); recs NT-load, h NT-store keep
// the 12.8MB xwh gather table resident in L2.

#define FEAT 128

typedef _Float16 half8 __attribute__((ext_vector_type(8)));
typedef _Float16 half4 __attribute__((ext_vector_type(4)));
typedef float f32x4 __attribute__((ext_vector_type(4)));
typedef unsigned int u32x4 __attribute__((ext_vector_type(4)));  // NT-loadable

__device__ __forceinline__ int lower_bound_i(const int* a, int n, int key) {
  int lo = 0, hi = n;
  while (lo < hi) { int mid = (lo + hi) >> 1; if (a[mid] < key) lo = mid + 1; else hi = mid; }
  return lo;
}

__device__ __forceinline__ float rec_w(unsigned int rc) {
  return (float)__builtin_bit_cast(_Float16, (unsigned short)(rc >> 16));
}

// ---- weight prep: blend + transpose -> fp16 ----
__global__ void prep_weights(const float* __restrict__ w1, const float* __restrict__ wr1,
                             const float* __restrict__ b1, const float* __restrict__ br1,
                             const float* __restrict__ w2, const float* __restrict__ b2,
                             const float* __restrict__ w3, const float* __restrict__ b3,
                             const float* __restrict__ wr, const float* __restrict__ br,
                             __half* __restrict__ Wt, float* __restrict__ beff) {
  __shared__ float tile[128][129];
  int l = blockIdx.x;
  const float* W  = (l == 0) ? w1 : ((l == 1) ? w2 : w3);
  const float* Wr = (l == 0) ? wr1 : wr;
  const float* B  = (l == 0) ? b1 : ((l == 1) ? b2 : b3);
  const float* Br = (l == 0) ? br1 : br;
  int t = threadIdx.x;
  for (int idx = t; idx < 128 * 128; idx += 256) {
    int k = idx >> 7, c = idx & 127;
    tile[k][c] = 0.95f * W[idx] + 0.05f * Wr[idx];
  }
  __syncthreads();
  __half* out = Wt + l * 128 * 128;
  for (int idx = t; idx < 128 * 128; idx += 256) {
    int c = idx >> 7, k = idx & 127;
    out[idx] = __float2half(tile[k][c]);
  }
  if (t < 128) beff[l * 128 + t] = 0.95f * B[t] + 0.05f * Br[t];
}

// ---- pass 0: per-group edge counts ----
__global__ __launch_bounds__(256) void group_count(const int* __restrict__ edge, int E,
                                                   int* __restrict__ gcnt, int rpg) {
  __shared__ int cnt8[8];
  int t = threadIdx.x;
  if (t < 8) cnt8[t] = 0;
  __syncthreads();
  long long e0 = (long long)E * blockIdx.x / gridDim.x;
  long long e1 = (long long)E * (blockIdx.x + 1) / gridDim.x;
  for (int e = (int)e0 + t; e < (int)e1; e += 256) {
    int r = __builtin_nontemporal_load(&edge[e]);
    atomicAdd(&cnt8[min(r / rpg, 7)], 1);
  }
  __syncthreads();
  if (t < 8) atomicAdd(&gcnt[t], cnt8[t]);
}

__global__ void scan8(const int* __restrict__ gcnt, int* __restrict__ goff,
                      int* __restrict__ gcur) {
  if (threadIdx.x == 0) {
    int acc = 0;
    for (int g = 0; g < 8; g++) { goff[g] = acc; gcur[g] = acc; acc += gcnt[g]; }
  }
}

// ---- pass 1: partition edges into 8 contiguous row-range buckets ----
__global__ __launch_bounds__(256) void partition_edges(const int* __restrict__ edge, int E,
                                                       int* __restrict__ gcur,
                                                       int* __restrict__ br,
                                                       int* __restrict__ bc, int rpg) {
  __shared__ int cnt8[8], base8[8], cur8[8];
  int t = threadIdx.x;
  if (t < 8) { cnt8[t] = 0; cur8[t] = 0; }
  __syncthreads();
  long long e0 = (long long)E * blockIdx.x / gridDim.x;
  long long e1 = (long long)E * (blockIdx.x + 1) / gridDim.x;
  for (int e = (int)e0 + t; e < (int)e1; e += 256) {
    int r = __builtin_nontemporal_load(&edge[e]);
    atomicAdd(&cnt8[min(r / rpg, 7)], 1);
  }
  __syncthreads();
  if (t < 8) base8[t] = atomicAdd(&gcur[t], cnt8[t]);
  __syncthreads();
  for (int e = (int)e0 + t; e < (int)e1; e += 256) {
    int r = __builtin_nontemporal_load(&edge[e]);
    int c = __builtin_nontemporal_load(&edge[E + e]);
    int g = min(r / rpg, 7);
    int p = base8[g] + atomicAdd(&cur8[g], 1);
    br[p] = r;
    bc[p] = c;
  }
}

// ---- per-row counts from bucketed rows (XCD-local atomic region) ----
__global__ __launch_bounds__(256) void count_rows(const int* __restrict__ br,
                                                  const int* __restrict__ goff,
                                                  const int* __restrict__ gcnt,
                                                  int* __restrict__ cnt, int nslice) {
  int g = blockIdx.x & 7, s = blockIdx.x >> 3;
  int lo = goff[g], c = gcnt[g];
  long long i0 = lo + (long long)c * s / nslice;
  long long i1 = lo + (long long)c * (s + 1) / nslice;
  for (int i = (int)i0 + threadIdx.x; i < (int)i1; i += 256)
    atomicAdd(&cnt[__builtin_nontemporal_load(&br[i])], 1);
}

__global__ void compute_dinv(const int* __restrict__ cnt, int n, float* __restrict__ dinv) {
  int i = blockIdx.x * blockDim.x + threadIdx.x;
  if (i < n) dinv[i] = rsqrtf((float)cnt[i] + 1.0f);  // +1 self-loop
}

// padded count: round each row up to a multiple of 16 (zero-recs fill the gap)
__global__ void scan1(const int* __restrict__ cnt, int n, int* __restrict__ bsum) {
  __shared__ int sdata[1024];
  int i = blockIdx.x * 1024 + threadIdx.x;
  sdata[threadIdx.x] = (i < n) ? ((cnt[i] + 15) & ~15) : 0;
  __syncthreads();
  for (int s = 512; s > 0; s >>= 1) {
    if (threadIdx.x < s) sdata[threadIdx.x] += sdata[threadIdx.x + s];
    __syncthreads();
  }
  if (threadIdx.x == 0) bsum[blockIdx.x] = sdata[0];
}

// single-wave exclusive scan over block sums (nb <= 64)
__global__ void scan2(int* __restrict__ bsum, int nb, int* __restrict__ start, int n) {
  int t = threadIdx.x;   // 64 threads
  int v = (t < nb) ? bsum[t] : 0;
  int s = v;
  for (int d = 1; d < 64; d <<= 1) {
    int o = __shfl_up(s, d, 64);
    if (t >= d) s += o;
  }
  if (t < nb) bsum[t] = s - v;   // exclusive
  if (t == 63) start[n] = s;     // grand total
}

__global__ void scan3(const int* __restrict__ cnt, int n, const int* __restrict__ bsum,
                      int* __restrict__ start, int* __restrict__ cursor) {
  __shared__ int sdata[1024];
  int tid = threadIdx.x;
  int i = blockIdx.x * 1024 + tid;
  int v = (i < n) ? ((cnt[i] + 15) & ~15) : 0;
  sdata[tid] = v;
  __syncthreads();
  for (int off = 1; off < 1024; off <<= 1) {
    int add = (tid >= off) ? sdata[tid - off] : 0;
    __syncthreads();
    sdata[tid] += add;
    __syncthreads();
  }
  if (i < n) {
    int sv = bsum[blockIdx.x] + sdata[tid] - v;  // exclusive (padded)
    start[i] = sv;
    cursor[i] = sv;
  }
}

// ---- pass 2: fill recs from bucket g on XCD g (blockIdx%8 == g) ----
__global__ __launch_bounds__(256) void fill_bucket(const int* __restrict__ br,
                                                   const int* __restrict__ bc,
                                                   const int* __restrict__ goff,
                                                   const int* __restrict__ gcnt,
                                                   const float* __restrict__ dinv,
                                                   int* __restrict__ cursor,
                                                   unsigned int* __restrict__ recs,
                                                   int nslice) {
  int g = blockIdx.x & 7, s = blockIdx.x >> 3;
  int lo = goff[g], c = gcnt[g];
  long long i0 = lo + (long long)c * s / nslice;
  long long i1 = lo + (long long)c * (s + 1) / nslice;
  for (int i = (int)i0 + threadIdx.x; i < (int)i1; i += 256) {
    int r = __builtin_nontemporal_load(&br[i]);
    int col = __builtin_nontemporal_load(&bc[i]);
    int pos = atomicAdd(&cursor[r], 1);
    unsigned short wb = __builtin_bit_cast(unsigned short, (_Float16)(dinv[r] * dinv[col]));
    recs[pos] = (unsigned int)col | ((unsigned int)wb << 16);
  }
}

// ---- MFMA GEMM (fp16 input): xwh[r][c] = fp16( sum_k Xh[r][k] * Wt[c][k] ) ----
__global__ __launch_bounds__(256) void gemm_mfma(const __half* __restrict__ Xh,
                                                 const __half* __restrict__ Wt,
                                                 __half* __restrict__ xwh, int ntile) {
  __shared__ __half Wlds[128 * 128];
  int t = threadIdx.x;
  #pragma unroll
  for (int it = 0; it < 8; it++) {
    int idx = t + it * 256;          // 2048 chunks of 16B
    int c = idx >> 4, ch = idx & 15;
    float4 v = *((const float4*)Wt + idx);
    int byte = ((c << 8) + (ch << 4)) ^ ((c & 7) << 4);
    *(float4*)((char*)Wlds + byte) = v;
  }
  __syncthreads();

  int wid = t >> 6, lane = t & 63;
  int tile = blockIdx.x * 4 + wid;
  if (tile >= ntile) return;
  int r = lane & 15, kg = lane >> 4;
  size_t rowbase = (size_t)tile * 16;

  const half8* aptr = (const half8*)(Xh + (rowbase + r) * FEAT + kg * 8);
  half8 a[4];
  #pragma unroll
  for (int ks = 0; ks < 4; ks++) a[ks] = aptr[ks * 4];   // k0 = ks*32 + kg*8

  f32x4 acc[8];
  #pragma unroll
  for (int nt = 0; nt < 8; nt++) acc[nt] = (f32x4){0.f, 0.f, 0.f, 0.f};

  #pragma unroll
  for (int nt = 0; nt < 8; nt++) {
    #pragma unroll
    for (int ks = 0; ks < 4; ks++) {
      int byte = ((((nt << 4) + r) << 8) + (ks << 6) + (kg << 4)) ^ ((r & 7) << 4);
      half8 b = *(const half8*)((const char*)Wlds + byte);
      acc[nt] = __builtin_amdgcn_mfma_f32_16x16x32_f16(a[ks], b, acc[nt], 0, 0, 0);
    }
  }

  int orow = kg * 4;
  #pragma unroll
  for (int nt = 0; nt < 8; nt++)
    #pragma unroll
    for (int j = 0; j < 4; j++)
      xwh[(rowbase + orow + j) * FEAT + (nt << 4) + r] = __float2half(acc[nt][j]);
}

// ---- MFMA GEMM (fp32 input, layer 1): converts x in-register (drops f2h pass) ----
__global__ __launch_bounds__(256) void gemm_mfma_l1(const float* __restrict__ X,
                                                    const __half* __restrict__ Wt,
                                                    __half* __restrict__ xwh, int ntile) {
  __shared__ __half Wlds[128 * 128];
  int t = threadIdx.x;
  #pragma unroll
  for (int it = 0; it < 8; it++) {
    int idx = t + it * 256;
    int c = idx >> 4, ch = idx & 15;
    float4 v = *((const float4*)Wt + idx);
    int byte = ((c << 8) + (ch << 4)) ^ ((c & 7) << 4);
    *(float4*)((char*)Wlds + byte) = v;
  }
  __syncthreads();

  int wid = t >> 6, lane = t & 63;
  int tile = blockIdx.x * 4 + wid;
  if (tile >= ntile) return;
  int r = lane & 15, kg = lane >> 4;
  size_t rowbase = (size_t)tile * 16;

  const float* aptr = X + (rowbase + r) * FEAT + kg * 8;
  half8 a[4];
  #pragma unroll
  for (int ks = 0; ks < 4; ks++) {
    float4 f0 = *(const float4*)(aptr + ks * 32);
    float4 f1 = *(const float4*)(aptr + ks * 32 + 4);
    a[ks] = (half8){(_Float16)f0.x, (_Float16)f0.y, (_Float16)f0.z, (_Float16)f0.w,
                    (_Float16)f1.x, (_Float16)f1.y, (_Float16)f1.z, (_Float16)f1.w};
  }

  f32x4 acc[8];
  #pragma unroll
  for (int nt = 0; nt < 8; nt++) acc[nt] = (f32x4){0.f, 0.f, 0.f, 0.f};

  #pragma unroll
  for (int nt = 0; nt < 8; nt++) {
    #pragma unroll
    for (int ks = 0; ks < 4; ks++) {
      int byte = ((((nt << 4) + r) << 8) + (ks << 6) + (kg << 4)) ^ ((r & 7) << 4);
      half8 b = *(const half8*)((const char*)Wlds + byte);
      acc[nt] = __builtin_amdgcn_mfma_f32_16x16x32_f16(a[ks], b, acc[nt], 0, 0, 0);
    }
  }

  int orow = kg * 4;
  #pragma unroll
  for (int nt = 0; nt < 8; nt++)
    #pragma unroll
    for (int j = 0; j < 4; j++)
      xwh[(rowbase + orow + j) * FEAT + (nt << 4) + r] = __float2half(acc[nt][j]);
}

// ---- pull aggregation: one wave/node; rows padded to x16 -> 16 gathers in flight.
// recs NT-load / h NT-store keep the xwh gather table L2-resident. ----
__global__ __launch_bounds__(256) void aggregate(
    const __half* __restrict__ xwh, const unsigned int* __restrict__ recs,
    const int* __restrict__ start, const float* __restrict__ dinv,
    const float* __restrict__ beff, __half* __restrict__ h, int n) {
  int wave = (blockIdx.x * blockDim.x + threadIdx.x) >> 6;
  int lane = threadIdx.x & 63;
  if (wave >= n) return;
  float di = dinv[wave];
  float2 sv = __half22float2(*(const __half2*)(xwh + (size_t)wave * FEAT + lane * 2));
  float wii = di * di;
  float a0 = sv.x * wii;
  float a1 = sv.y * wii;
  int s = start[wave], e = start[wave + 1];   // e - s is a multiple of 16
  for (int idx = s; idx < e; idx += 16) {
    u32x4 r0 = __builtin_nontemporal_load((const u32x4*)(recs + idx));
    u32x4 r1 = __builtin_nontemporal_load((const u32x4*)(recs + idx + 4));
    u32x4 r2 = __builtin_nontemporal_load((const u32x4*)(recs + idx + 8));
    u32x4 r3 = __builtin_nontemporal_load((const u32x4*)(recs + idx + 12));
    unsigned int rc[16] = {r0.x, r0.y, r0.z, r0.w, r1.x, r1.y, r1.z, r1.w,
                           r2.x, r2.y, r2.z, r2.w, r3.x, r3.y, r3.z, r3.w};
    float2 u[16];
    #pragma unroll
    for (int q = 0; q < 16; q++)
      u[q] = __half22float2(
          *(const __half2*)(xwh + (size_t)(rc[q] & 0xffffu) * FEAT + lane * 2));
    #pragma unroll
    for (int q = 0; q < 16; q++) {
      float w = rec_w(rc[q]);
      a0 += u[q].x * w; a1 += u[q].y * w;
    }
  }
  float2 b = *(const float2*)(beff + lane * 2);
  a0 = fmaxf(a0 + b.x, 0.f);
  a1 = fmaxf(a1 + b.y, 0.f);
  __half2 hv = __float22half2_rn(make_float2(a0, a1));
  __builtin_nontemporal_store(__builtin_bit_cast(unsigned int, hv),
                              (unsigned int*)(h + (size_t)wave * FEAT + lane * 2));
}

// ---- fused mean-pool + lin1 + relu + lin2 + log_softmax (256 threads) ----
// 16 row-groups x 16 lanes, half8 (16B) loads -> 48 16B loads in flight/block.
__global__ __launch_bounds__(256) void pool_mlp(
    const __half* __restrict__ h1, const __half* __restrict__ h2,
    const __half* __restrict__ h3, const int* __restrict__ batch, int n,
    const float* __restrict__ lin1w, const float* __restrict__ lin1b,
    const float* __restrict__ lin2w, const float* __restrict__ lin2b,
    float* __restrict__ out) {
  __shared__ float part[16][384];
  __shared__ float mean[384];
  __shared__ float tvec[128];
  __shared__ float logits[10];
  __shared__ float red[2];
  int g = blockIdx.x;
  int t = threadIdx.x;   // 256 threads
  int lo = lower_bound_i(batch, n, g);
  int hi = lower_bound_i(batch, n, g + 1);
  int rg = t >> 4, l16 = t & 15;   // 16 row-groups x 16 lanes (8 halfs each)
  float s1[8] = {0,0,0,0,0,0,0,0}, s2[8] = {0,0,0,0,0,0,0,0}, s3[8] = {0,0,0,0,0,0,0,0};
  for (int i = lo + rg; i < hi; i += 16) {
    half8 v1 = *((const half8*)(h1 + (size_t)i * FEAT) + l16);
    half8 v2 = *((const half8*)(h2 + (size_t)i * FEAT) + l16);
    half8 v3 = *((const half8*)(h3 + (size_t)i * FEAT) + l16);
    #pragma unroll
    for (int q = 0; q < 8; q++) {
      s1[q] += (float)v1[q]; s2[q] += (float)v2[q]; s3[q] += (float)v3[q];
    }
  }
  #pragma unroll
  for (int q = 0; q < 8; q++) {
    part[rg][l16 * 8 + q]       = s1[q];
    part[rg][128 + l16 * 8 + q] = s2[q];
    part[rg][256 + l16 * 8 + q] = s3[q];
  }
  __syncthreads();
  float invc = 1.0f / fmaxf((float)(hi - lo), 1.0f);
  for (int j = t; j < 384; j += 256) {
    float acc = 0.f;
    #pragma unroll
    for (int r = 0; r < 16; r++) acc += part[r][j];
    mean[j] = acc * invc;
  }
  __syncthreads();
  if (t < 128) {
    float acc = lin1b[t];
    for (int k = 0; k < 384; k++) acc += mean[k] * lin1w[k * 128 + t];
    tvec[t] = fmaxf(acc, 0.f);
  }
  __syncthreads();
  if (t < 10) {
    float a = lin2b[t];
    for (int k = 0; k < 128; k++) a += tvec[k] * lin2w[k * 10 + t];
    logits[t] = a;
  }
  __syncthreads();
  if (t == 0) {
    float m = -1e30f;
    for (int j = 0; j < 10; j++) m = fmaxf(m, logits[j]);
    float se = 0.f;
    for (int j = 0; j < 10; j++) se += expf(logits[j] - m);
    red[0] = m; red[1] = logf(se);
  }
  __syncthreads();
  if (t < 10) out[g * 10 + t] = logits[t] - red[0] - red[1];
}

extern "C" void kernel_launch(void* const* d_in, const int* in_sizes, int n_in,
                              void* d_out, int out_size, void* d_ws, size_t ws_size,
                              hipStream_t stream) {
  const float* x     = (const float*)d_in[0];
  const int*   edge  = (const int*)d_in[1];
  const int*   batch = (const int*)d_in[2];
  const float* w1    = (const float*)d_in[3];
  const float* b1    = (const float*)d_in[4];
  const float* wr1   = (const float*)d_in[5];
  const float* br1   = (const float*)d_in[6];
  const float* w2    = (const float*)d_in[7];
  const float* b2    = (const float*)d_in[8];
  const float* w3    = (const float*)d_in[9];
  const float* b3    = (const float*)d_in[10];
  const float* wr    = (const float*)d_in[11];
  const float* br    = (const float*)d_in[12];
  const float* lin1w = (const float*)d_in[13];
  const float* lin1b = (const float*)d_in[14];
  const float* lin2w = (const float*)d_in[15];
  const float* lin2b = (const float*)d_in[16];

  int n  = in_sizes[0] / FEAT;   // 50000
  int E  = in_sizes[1] / 2;      // 800000
  int ng = out_size / 10;        // 512
  int rpg = n >> 3;              // rows per group

  char* p = (char*)d_ws;
  auto carve = [&](size_t bytes) -> void* {
    void* r = (void*)p;
    p += (bytes + 255) & ~(size_t)255;
    return r;
  };
  size_t recs_cap = (size_t)E + 16 * (size_t)n;   // padded upper bound
  __half*       Wt     = (__half*)carve(3 * 128 * 128 * sizeof(__half));
  float*        beff   = (float*)carve(3 * 128 * sizeof(float));
  int*          cnt    = (int*)carve((size_t)n * sizeof(int));
  int*          cursor = (int*)carve((size_t)n * sizeof(int));
  int*          start  = (int*)carve((size_t)(n + 1) * sizeof(int));
  int*          bsum   = (int*)carve(64 * sizeof(int));
  int*          gcnt   = (int*)carve(8 * sizeof(int));
  int*          goff   = (int*)carve(8 * sizeof(int));
  int*          gcur   = (int*)carve(8 * sizeof(int));
  int*          brow   = (int*)carve((size_t)E * sizeof(int));
  int*          bcol   = (int*)carve((size_t)E * sizeof(int));
  unsigned int* recs   = (unsigned int*)carve(recs_cap * sizeof(unsigned int));
  float*        dinv   = (float*)carve((size_t)n * sizeof(float));
  __half*       xwh    = (__half*)carve((size_t)n * FEAT * sizeof(__half));
  __half*       h1     = (__half*)carve((size_t)n * FEAT * sizeof(__half));
  __half*       h2     = (__half*)carve((size_t)n * FEAT * sizeof(__half));
  __half*       h3     = (__half*)carve((size_t)n * FEAT * sizeof(__half));

  hipMemsetAsync(cnt, 0, (size_t)n * sizeof(int), stream);
  hipMemsetAsync(gcnt, 0, 8 * sizeof(int), stream);
  hipMemsetAsync(recs, 0, recs_cap * sizeof(unsigned int), stream);

  prep_weights<<<3, 256, 0, stream>>>(w1, wr1, b1, br1, w2, b2, w3, b3, wr, br, Wt, beff);

  // CSR build
  group_count<<<1024, 256, 0, stream>>>(edge, E, gcnt, rpg);
  scan8<<<1, 64, 0, stream>>>(gcnt, goff, gcur);
  partition_edges<<<1024, 256, 0, stream>>>(edge, E, gcur, brow, bcol, rpg);
  count_rows<<<1024, 256, 0, stream>>>(brow, goff, gcnt, cnt, 1024 / 8);
  compute_dinv<<<(n + 255) / 256, 256, 0, stream>>>(cnt, n, dinv);
  int nb = (n + 1023) / 1024;
  scan1<<<nb, 1024, 0, stream>>>(cnt, n, bsum);
  scan2<<<1, 64, 0, stream>>>(bsum, nb, start, n);
  scan3<<<nb, 1024, 0, stream>>>(cnt, n, bsum, start, cursor);
  fill_bucket<<<2048, 256, 0, stream>>>(brow, bcol, goff, gcnt, dinv, cursor, recs,
                                        2048 / 8);

  int ntile = (n + 15) / 16;            // 3125
  int gb = (ntile + 3) / 4;             // 4 waves/block
  int ab = (n * 64 + 255) / 256;

  gemm_mfma_l1<<<gb, 256, 0, stream>>>(x, Wt, xwh, ntile);
  aggregate<<<ab, 256, 0, stream>>>(xwh, recs, start, dinv, beff, h1, n);

  gemm_mfma<<<gb, 256, 0, stream>>>(h1, Wt + 128 * 128, xwh, ntile);
  aggregate<<<ab, 256, 0, stream>>>(xwh, recs, start, dinv, beff + 128, h2, n);

  gemm_mfma<<<gb, 256, 0, stream>>>(h2, Wt + 2 * 128 * 128, xwh, ntile);
  aggregate<<<ab, 256, 0, stream>>>(xwh, recs, start, dinv, beff + 256, h3, n);

  pool_mlp<<<ng, 256, 0, stream>>>(h1, h2, h3, batch, n, lin1w, lin1b, lin2w, lin2b,
                                   (float*)d_out);
}

// Round 12
// 263.394 us; speedup vs baseline: 1.6023x; 1.0845x over previous
//
#include <hip/hip_runtime.h>
#include <hip/hip_fp16.h>

// GCNWithJK on MI355X.
// Layers collapse to one GEMM each: W_eff = 0.95*W + 0.05*Wr (linearity of Agg).
// All activations fp16; GEMMs use v_mfma_f32_16x16x32_f16 (fp32 accum); layer-1
// GEMM reads fp32 x directly and is MERGED with fill_part (independent stages
// overlap in one dispatch: gemm blocks first, fill blocks after).
// CSR build (simple chain, round-7 proven): count_edges -> scan1(+dinv) ->
// wave-scan2 -> scan3 -> fill_part (8 row-groups x 256 slices, group=blockIdx&7).
// Aggregate: one wave/node, rows padded to x16 -> 16 gathers ALWAYS in flight
// (pad slots read row 0 with w=0: exact no-op); recs NT-load, h NT-store.

#define FEAT 128

typedef _Float16 half8 __attribute__((ext_vector_type(8)));
typedef float f32x4 __attribute__((ext_vector_type(4)));
typedef unsigned int u32x4 __attribute__((ext_vector_type(4)));  // NT-loadable

__device__ __forceinline__ int lower_bound_i(const int* a, int n, int key) {
  int lo = 0, hi = n;
  while (lo < hi) { int mid = (lo + hi) >> 1; if (a[mid] < key) lo = mid + 1; else hi = mid; }
  return lo;
}

__device__ __forceinline__ float rec_w(unsigned int rc) {
  return (float)__builtin_bit_cast(_Float16, (unsigned short)(rc >> 16));
}

// ---- weight prep: blend + transpose -> fp16 ----
__global__ void prep_weights(const float* __restrict__ w1, const float* __restrict__ wr1,
                             const float* __restrict__ b1, const float* __restrict__ br1,
                             const float* __restrict__ w2, const float* __restrict__ b2,
                             const float* __restrict__ w3, const float* __restrict__ b3,
                             const float* __restrict__ wr, const float* __restrict__ br,
                             __half* __restrict__ Wt, float* __restrict__ beff) {
  __shared__ float tile[128][129];
  int l = blockIdx.x;
  const float* W  = (l == 0) ? w1 : ((l == 1) ? w2 : w3);
  const float* Wr = (l == 0) ? wr1 : wr;
  const float* B  = (l == 0) ? b1 : ((l == 1) ? b2 : b3);
  const float* Br = (l == 0) ? br1 : br;
  int t = threadIdx.x;
  for (int idx = t; idx < 128 * 128; idx += 256) {
    int k = idx >> 7, c = idx & 127;
    tile[k][c] = 0.95f * W[idx] + 0.05f * Wr[idx];
  }
  __syncthreads();
  __half* out = Wt + l * 128 * 128;
  for (int idx = t; idx < 128 * 128; idx += 256) {
    int c = idx >> 7, k = idx & 127;
    out[idx] = __float2half(tile[k][c]);
  }
  if (t < 128) beff[l * 128 + t] = 0.95f * B[t] + 0.05f * Br[t];
}

// ---- CSR: count ----
__global__ void count_edges(const int* __restrict__ row, int E, int* __restrict__ cnt) {
  int e = blockIdx.x * blockDim.x + threadIdx.x;
  if (e < E) atomicAdd(&cnt[__builtin_nontemporal_load(&row[e])], 1);
}

// ---- scan1 + dinv fused: block sums of pad16(cnt), dinv = rsqrt(cnt+1) ----
__global__ void scan1_dinv(const int* __restrict__ cnt, int n, int* __restrict__ bsum,
                           float* __restrict__ dinv) {
  __shared__ int sdata[1024];
  int i = blockIdx.x * 1024 + threadIdx.x;
  int c = (i < n) ? cnt[i] : 0;
  if (i < n) dinv[i] = rsqrtf((float)c + 1.0f);  // +1 self-loop
  sdata[threadIdx.x] = (i < n) ? ((c + 15) & ~15) : 0;
  __syncthreads();
  for (int s = 512; s > 0; s >>= 1) {
    if (threadIdx.x < s) sdata[threadIdx.x] += sdata[threadIdx.x + s];
    __syncthreads();
  }
  if (threadIdx.x == 0) bsum[blockIdx.x] = sdata[0];
}

// single-wave exclusive scan over block sums (nb <= 64)
__global__ void scan2(int* __restrict__ bsum, int nb, int* __restrict__ start, int n) {
  int t = threadIdx.x;   // 64 threads
  int v = (t < nb) ? bsum[t] : 0;
  int s = v;
  for (int d = 1; d < 64; d <<= 1) {
    int o = __shfl_up(s, d, 64);
    if (t >= d) s += o;
  }
  if (t < nb) bsum[t] = s - v;   // exclusive
  if (t == 63) start[n] = s;     // grand total
}

__global__ void scan3(const int* __restrict__ cnt, int n, const int* __restrict__ bsum,
                      int* __restrict__ start, int* __restrict__ cursor) {
  __shared__ int sdata[1024];
  int tid = threadIdx.x;
  int i = blockIdx.x * 1024 + tid;
  int v = (i < n) ? ((cnt[i] + 15) & ~15) : 0;
  sdata[tid] = v;
  __syncthreads();
  for (int off = 1; off < 1024; off <<= 1) {
    int add = (tid >= off) ? sdata[tid - off] : 0;
    __syncthreads();
    sdata[tid] += add;
    __syncthreads();
  }
  if (i < n) {
    int sv = bsum[blockIdx.x] + sdata[tid] - v;  // exclusive (padded)
    start[i] = sv;
    cursor[i] = sv;
  }
}

// ---- MERGED: layer-1 GEMM (fp32 x, in-register f16 convert) + fill_part ----
// blocks [0, gb): gemm tiles; blocks [gb, gb+2048): fill slices.
// The two stages are independent (gemm needs prep; fill needs scan3) -> overlap.
__global__ __launch_bounds__(256) void gemm_l1_fill(
    const float* __restrict__ X, const __half* __restrict__ Wt,
    __half* __restrict__ xwh, int ntile, int gb,
    const int* __restrict__ edge, int E, const float* __restrict__ dinv,
    int* __restrict__ cursor, unsigned int* __restrict__ recs, int n) {
  __shared__ __half Wlds[128 * 128];
  int b = blockIdx.x;
  if (b >= gb) {
    // ---- fill path: XCD-partitioned scatter (group = fb&7, slice = fb>>3) ----
    int fb = b - gb;
    int g = fb & 7, s = fb >> 3;
    const int nslice = 256;
    int rpg = n >> 3;
    int rlo = g * rpg;
    int rhi = (g == 7) ? n : rlo + rpg;
    long long e0 = (long long)E * s / nslice;
    long long e1 = (long long)E * (s + 1) / nslice;
    for (int e = (int)e0 + threadIdx.x; e < (int)e1; e += 256) {
      int r = __builtin_nontemporal_load(&edge[e]);
      if (r >= rlo && r < rhi) {
        int c = __builtin_nontemporal_load(&edge[E + e]);
        int pos = atomicAdd(&cursor[r], 1);
        unsigned short wb =
            __builtin_bit_cast(unsigned short, (_Float16)(dinv[r] * dinv[c]));
        recs[pos] = (unsigned int)c | ((unsigned int)wb << 16);
      }
    }
    return;
  }
  // ---- gemm path ----
  int t = threadIdx.x;
  #pragma unroll
  for (int it = 0; it < 8; it++) {
    int idx = t + it * 256;
    int c = idx >> 4, ch = idx & 15;
    float4 v = *((const float4*)Wt + idx);
    int byte = ((c << 8) + (ch << 4)) ^ ((c & 7) << 4);
    *(float4*)((char*)Wlds + byte) = v;
  }
  __syncthreads();

  int wid = t >> 6, lane = t & 63;
  int tile = b * 4 + wid;
  if (tile >= ntile) return;
  int r = lane & 15, kg = lane >> 4;
  size_t rowbase = (size_t)tile * 16;

  const float* aptr = X + (rowbase + r) * FEAT + kg * 8;
  half8 a[4];
  #pragma unroll
  for (int ks = 0; ks < 4; ks++) {
    float4 f0 = *(const float4*)(aptr + ks * 32);
    float4 f1 = *(const float4*)(aptr + ks * 32 + 4);
    a[ks] = (half8){(_Float16)f0.x, (_Float16)f0.y, (_Float16)f0.z, (_Float16)f0.w,
                    (_Float16)f1.x, (_Float16)f1.y, (_Float16)f1.z, (_Float16)f1.w};
  }

  f32x4 acc[8];
  #pragma unroll
  for (int nt = 0; nt < 8; nt++) acc[nt] = (f32x4){0.f, 0.f, 0.f, 0.f};

  #pragma unroll
  for (int nt = 0; nt < 8; nt++) {
    #pragma unroll
    for (int ks = 0; ks < 4; ks++) {
      int byte = ((((nt << 4) + r) << 8) + (ks << 6) + (kg << 4)) ^ ((r & 7) << 4);
      half8 bb = *(const half8*)((const char*)Wlds + byte);
      acc[nt] = __builtin_amdgcn_mfma_f32_16x16x32_f16(a[ks], bb, acc[nt], 0, 0, 0);
    }
  }

  int orow = kg * 4;
  #pragma unroll
  for (int nt = 0; nt < 8; nt++)
    #pragma unroll
    for (int j = 0; j < 4; j++)
      xwh[(rowbase + orow + j) * FEAT + (nt << 4) + r] = __float2half(acc[nt][j]);
}

// ---- MFMA GEMM (fp16 input): xwh[r][c] = fp16( sum_k Xh[r][k] * Wt[c][k] ) ----
__global__ __launch_bounds__(256) void gemm_mfma(const __half* __restrict__ Xh,
                                                 const __half* __restrict__ Wt,
                                                 __half* __restrict__ xwh, int ntile) {
  __shared__ __half Wlds[128 * 128];
  int t = threadIdx.x;
  #pragma unroll
  for (int it = 0; it < 8; it++) {
    int idx = t + it * 256;          // 2048 chunks of 16B
    int c = idx >> 4, ch = idx & 15;
    float4 v = *((const float4*)Wt + idx);
    int byte = ((c << 8) + (ch << 4)) ^ ((c & 7) << 4);
    *(float4*)((char*)Wlds + byte) = v;
  }
  __syncthreads();

  int wid = t >> 6, lane = t & 63;
  int tile = blockIdx.x * 4 + wid;
  if (tile >= ntile) return;
  int r = lane & 15, kg = lane >> 4;
  size_t rowbase = (size_t)tile * 16;

  const half8* aptr = (const half8*)(Xh + (rowbase + r) * FEAT + kg * 8);
  half8 a[4];
  #pragma unroll
  for (int ks = 0; ks < 4; ks++) a[ks] = aptr[ks * 4];   // k0 = ks*32 + kg*8

  f32x4 acc[8];
  #pragma unroll
  for (int nt = 0; nt < 8; nt++) acc[nt] = (f32x4){0.f, 0.f, 0.f, 0.f};

  #pragma unroll
  for (int nt = 0; nt < 8; nt++) {
    #pragma unroll
    for (int ks = 0; ks < 4; ks++) {
      int byte = ((((nt << 4) + r) << 8) + (ks << 6) + (kg << 4)) ^ ((r & 7) << 4);
      half8 b = *(const half8*)((const char*)Wlds + byte);
      acc[nt] = __builtin_amdgcn_mfma_f32_16x16x32_f16(a[ks], b, acc[nt], 0, 0, 0);
    }
  }

  int orow = kg * 4;
  #pragma unroll
  for (int nt = 0; nt < 8; nt++)
    #pragma unroll
    for (int j = 0; j < 4; j++)
      xwh[(rowbase + orow + j) * FEAT + (nt << 4) + r] = __float2half(acc[nt][j]);
}

// ---- pull aggregation: one wave/node; rows padded to x16 -> 16 gathers in flight.
// recs NT-load / h NT-store. ----
__global__ __launch_bounds__(256) void aggregate(
    const __half* __restrict__ xwh, const unsigned int* __restrict__ recs,
    const int* __restrict__ start, const float* __restrict__ dinv,
    const float* __restrict__ beff, __half* __restrict__ h, int n) {
  int wave = (blockIdx.x * blockDim.x + threadIdx.x) >> 6;
  int lane = threadIdx.x & 63;
  if (wave >= n) return;
  float di = dinv[wave];
  float2 sv = __half22float2(*(const __half2*)(xwh + (size_t)wave * FEAT + lane * 2));
  float wii = di * di;
  float a0 = sv.x * wii;
  float a1 = sv.y * wii;
  int s = start[wave], e = start[wave + 1];   // e - s is a multiple of 16
  for (int idx = s; idx < e; idx += 16) {
    u32x4 r0 = __builtin_nontemporal_load((const u32x4*)(recs + idx));
    u32x4 r1 = __builtin_nontemporal_load((const u32x4*)(recs + idx + 4));
    u32x4 r2 = __builtin_nontemporal_load((const u32x4*)(recs + idx + 8));
    u32x4 r3 = __builtin_nontemporal_load((const u32x4*)(recs + idx + 12));
    unsigned int rc[16] = {r0.x, r0.y, r0.z, r0.w, r1.x, r1.y, r1.z, r1.w,
                           r2.x, r2.y, r2.z, r2.w, r3.x, r3.y, r3.z, r3.w};
    float2 u[16];
    #pragma unroll
    for (int q = 0; q < 16; q++)
      u[q] = __half22float2(
          *(const __half2*)(xwh + (size_t)(rc[q] & 0xffffu) * FEAT + lane * 2));
    #pragma unroll
    for (int q = 0; q < 16; q++) {
      float w = rec_w(rc[q]);
      a0 += u[q].x * w; a1 += u[q].y * w;
    }
  }
  float2 b = *(const float2*)(beff + lane * 2);
  a0 = fmaxf(a0 + b.x, 0.f);
  a1 = fmaxf(a1 + b.y, 0.f);
  __half2 hv = __float22half2_rn(make_float2(a0, a1));
  __builtin_nontemporal_store(__builtin_bit_cast(unsigned int, hv),
                              (unsigned int*)(h + (size_t)wave * FEAT + lane * 2));
}

// ---- fused mean-pool + lin1 + relu + lin2 + log_softmax (256 threads) ----
__global__ __launch_bounds__(256) void pool_mlp(
    const __half* __restrict__ h1, const __half* __restrict__ h2,
    const __half* __restrict__ h3, const int* __restrict__ batch, int n,
    const float* __restrict__ lin1w, const float* __restrict__ lin1b,
    const float* __restrict__ lin2w, const float* __restrict__ lin2b,
    float* __restrict__ out) {
  __shared__ float part[16][384];
  __shared__ float mean[384];
  __shared__ float tvec[128];
  __shared__ float logits[10];
  __shared__ float red[2];
  int g = blockIdx.x;
  int t = threadIdx.x;   // 256 threads
  int lo = lower_bound_i(batch, n, g);
  int hi = lower_bound_i(batch, n, g + 1);
  int rg = t >> 4, l16 = t & 15;   // 16 row-groups x 16 lanes (8 halfs each)
  float s1[8] = {0,0,0,0,0,0,0,0}, s2[8] = {0,0,0,0,0,0,0,0}, s3[8] = {0,0,0,0,0,0,0,0};
  for (int i = lo + rg; i < hi; i += 16) {
    half8 v1 = *((const half8*)(h1 + (size_t)i * FEAT) + l16);
    half8 v2 = *((const half8*)(h2 + (size_t)i * FEAT) + l16);
    half8 v3 = *((const half8*)(h3 + (size_t)i * FEAT) + l16);
    #pragma unroll
    for (int q = 0; q < 8; q++) {
      s1[q] += (float)v1[q]; s2[q] += (float)v2[q]; s3[q] += (float)v3[q];
    }
  }
  #pragma unroll
  for (int q = 0; q < 8; q++) {
    part[rg][l16 * 8 + q]       = s1[q];
    part[rg][128 + l16 * 8 + q] = s2[q];
    part[rg][256 + l16 * 8 + q] = s3[q];
  }
  __syncthreads();
  float invc = 1.0f / fmaxf((float)(hi - lo), 1.0f);
  for (int j = t; j < 384; j += 256) {
    float acc = 0.f;
    #pragma unroll
    for (int r = 0; r < 16; r++) acc += part[r][j];
    mean[j] = acc * invc;
  }
  __syncthreads();
  if (t < 128) {
    float acc = lin1b[t];
    for (int k = 0; k < 384; k++) acc += mean[k] * lin1w[k * 128 + t];
    tvec[t] = fmaxf(acc, 0.f);
  }
  __syncthreads();
  if (t < 10) {
    float a = lin2b[t];
    for (int k = 0; k < 128; k++) a += tvec[k] * lin2w[k * 10 + t];
    logits[t] = a;
  }
  __syncthreads();
  if (t == 0) {
    float m = -1e30f;
    for (int j = 0; j < 10; j++) m = fmaxf(m, logits[j]);
    float se = 0.f;
    for (int j = 0; j < 10; j++) se += expf(logits[j] - m);
    red[0] = m; red[1] = logf(se);
  }
  __syncthreads();
  if (t < 10) out[g * 10 + t] = logits[t] - red[0] - red[1];
}

extern "C" void kernel_launch(void* const* d_in, const int* in_sizes, int n_in,
                              void* d_out, int out_size, void* d_ws, size_t ws_size,
                              hipStream_t stream) {
  const float* x     = (const float*)d_in[0];
  const int*   edge  = (const int*)d_in[1];
  const int*   batch = (const int*)d_in[2];
  const float* w1    = (const float*)d_in[3];
  const float* b1    = (const float*)d_in[4];
  const float* wr1   = (const float*)d_in[5];
  const float* br1   = (const float*)d_in[6];
  const float* w2    = (const float*)d_in[7];
  const float* b2    = (const float*)d_in[8];
  const float* w3    = (const float*)d_in[9];
  const float* b3    = (const float*)d_in[10];
  const float* wr    = (const float*)d_in[11];
  const float* br    = (const float*)d_in[12];
  const float* lin1w = (const float*)d_in[13];
  const float* lin1b = (const float*)d_in[14];
  const float* lin2w = (const float*)d_in[15];
  const float* lin2b = (const float*)d_in[16];

  int n  = in_sizes[0] / FEAT;   // 50000
  int E  = in_sizes[1] / 2;      // 800000
  int ng = out_size / 10;        // 512

  char* p = (char*)d_ws;
  auto carve = [&](size_t bytes) -> void* {
    void* r = (void*)p;
    p += (bytes + 255) & ~(size_t)255;
    return r;
  };
  size_t recs_cap = (size_t)E + 16 * (size_t)n;   // padded upper bound
  __half*       Wt     = (__half*)carve(3 * 128 * 128 * sizeof(__half));
  float*        beff   = (float*)carve(3 * 128 * sizeof(float));
  int*          cnt    = (int*)carve((size_t)n * sizeof(int));
  int*          cursor = (int*)carve((size_t)n * sizeof(int));
  int*          start  = (int*)carve((size_t)(n + 1) * sizeof(int));
  int*          bsum   = (int*)carve(64 * sizeof(int));
  unsigned int* recs   = (unsigned int*)carve(recs_cap * sizeof(unsigned int));
  float*        dinv   = (float*)carve((size_t)n * sizeof(float));
  __half*       xwh    = (__half*)carve((size_t)n * FEAT * sizeof(__half));
  __half*       h1     = (__half*)carve((size_t)n * FEAT * sizeof(__half));
  __half*       h2     = (__half*)carve((size_t)n * FEAT * sizeof(__half));
  __half*       h3     = (__half*)carve((size_t)n * FEAT * sizeof(__half));

  hipMemsetAsync(cnt, 0, (size_t)n * sizeof(int), stream);
  hipMemsetAsync(recs, 0, recs_cap * sizeof(unsigned int), stream);

  prep_weights<<<3, 256, 0, stream>>>(w1, wr1, b1, br1, w2, b2, w3, b3, wr, br, Wt, beff);

  int eb = (E + 255) / 256;
  count_edges<<<eb, 256, 0, stream>>>(edge, E, cnt);
  int nb = (n + 1023) / 1024;
  scan1_dinv<<<nb, 1024, 0, stream>>>(cnt, n, bsum, dinv);
  scan2<<<1, 64, 0, stream>>>(bsum, nb, start, n);
  scan3<<<nb, 1024, 0, stream>>>(cnt, n, bsum, start, cursor);

  int ntile = (n + 15) / 16;            // 3125
  int gb = (ntile + 3) / 4;             // 782 gemm blocks (4 waves each)
  int ab = (n * 64 + 255) / 256;

  // merged: layer-1 GEMM overlapped with CSR fill (independent stages)
  gemm_l1_fill<<<gb + 2048, 256, 0, stream>>>(x, Wt, xwh, ntile, gb,
                                              edge, E, dinv, cursor, recs, n);
  aggregate<<<ab, 256, 0, stream>>>(xwh, recs, start, dinv, beff, h1, n);

  gemm_mfma<<<gb, 256, 0, stream>>>(h1, Wt + 128 * 128, xwh, ntile);
  aggregate<<<ab, 256, 0, stream>>>(xwh, recs, start, dinv, beff + 128, h2, n);

  gemm_mfma<<<gb, 256, 0, stream>>>(h2, Wt + 2 * 128 * 128, xwh, ntile);
  aggregate<<<ab, 256, 0, stream>>>(xwh, recs, start, dinv, beff + 256, h3, n);

  pool_mlp<<<ng, 256, 0, stream>>>(h1, h2, h3, batch, n, lin1w, lin1b, lin2w, lin2b,
                                   (float*)d_out);
}